// Round 4
// baseline (1553.353 us; speedup 1.0000x reference)
//
#include <hip/hip_runtime.h>
#include <stdint.h>

// CIN layers: Xn[b,h,d] = sum_{j,k} W[h,j,k] * X0[b,j,d] * Xi[b,k,d] + bias[h]
// Factored:   y[h,j,d]  = sum_k Wbf16[h,j,k] * Xibf16[b,k,d]   (MFMA 16x16x32 bf16)
//             Xn[b,h,d] = sum_j X0[b,j,d] * y + bias            (f32 FMA)
// Grid: 1024 blocks = 256 b-groups x 4 h-quarters; block = 4 waves x (4 b) x 32 h.
// K split into 64-wide passes (stage = 32h x 64k = 4KB LDS, VGPR-bounce staged,
// one barrier per stage, double buffered). 4 blocks/CU for latency hiding.
// R3 bug: staging used byte offset 8192 for buffer 1, but a buffer is 4096 B
// (32*64 shorts) -> odd stages read never-written LDS and clobbered x0s -> NaN.
// Fix: typed &Wlds[buf][0] addressing everywhere.

#define NB_F0 39
#define NB_H  128
#define NB_B  4096

typedef float f32x4 __attribute__((ext_vector_type(4)));
typedef short s16x8 __attribute__((ext_vector_type(8)));

__device__ __forceinline__ unsigned short rne_bf16(float f) {
  union { float f; unsigned u; } v; v.f = f;
  return (unsigned short)((v.u + 0x7fffu + ((v.u >> 16) & 1u)) >> 16);
}
__device__ __forceinline__ float bf16_to_f32(unsigned short s) {
  union { unsigned u; float f; } v; v.u = ((unsigned)s) << 16;
  return v.f;
}

// X0 f32 [B][39][16] -> X0T bf16 [B][16][64], zero-padded j>=39
__global__ void prep_x0_kernel(const float* __restrict__ X0g,
                               unsigned short* __restrict__ X0T) {
  const int b = blockIdx.x;
  const int t = threadIdx.x;
  const int d  = t >> 4;
  const int k4 = (t & 15) << 2;
  unsigned short vv[4];
#pragma unroll
  for (int i = 0; i < 4; ++i) {
    const int k = k4 + i;
    vv[i] = (k < NB_F0) ? rne_bf16(X0g[(size_t)b * (NB_F0 * 16) + k * 16 + d])
                        : (unsigned short)0;
  }
  ushort4 pk; pk.x = vv[0]; pk.y = vv[1]; pk.z = vv[2]; pk.w = vv[3];
  *(ushort4*)&X0T[((size_t)b * 16 + d) * 64 + k4] = pk;
}

// W f32 [128][39*Fi] -> Wp bf16 [39][128][Fi_pad].
// 8-short chunks XOR-swizzled by (h&7) WITHIN each 64-short group so that
// 64k-windowed staging remains self-contained. Pad k>=Fi with 0.
__global__ void prep_w_kernel(const float* __restrict__ Wsrc,
                              unsigned short* __restrict__ Wdst,
                              int Fi, int Fi_pad, int total) {
  int idx = blockIdx.x * 256 + threadIdx.x;
  if (idx >= total) return;
  int j   = idx / (NB_H * Fi_pad);
  int rem = idx - j * (NB_H * Fi_pad);
  int h   = rem / Fi_pad;
  int kp  = rem - h * Fi_pad;
  int cp = kp >> 3, p = kp & 7;
  int cl = (cp & ~7) | ((cp ^ h) & 7);
  int kl = (cl << 3) | p;
  unsigned short v = 0;
  if (kl < Fi) v = rne_bf16(Wsrc[(size_t)h * (NB_F0 * Fi) + j * Fi + kl]);
  Wdst[idx] = v;
}

template <int FI_PAD, bool STORE_XN>
__global__ __launch_bounds__(256, 4) void cin_layer(
    const unsigned short* __restrict__ Wp,   // [39][128][FI_PAD] bf16 swizzled
    const unsigned short* __restrict__ XiT,  // [B][16][FI_PAD] bf16
    const unsigned short* __restrict__ X0T,  // [B][16][64] bf16
    const float* __restrict__ bias,          // [128]
    unsigned short* __restrict__ XnT,        // [B][16][128] bf16 (or unused)
    float* __restrict__ outp)                // d_out + layer*128, stride 384
{
  constexpr int KPASS = FI_PAD / 64;   // 1 or 2 K-passes of 64
  constexpr int S = NB_F0 * KPASS;     // stages

  __shared__ __attribute__((aligned(16))) unsigned short Wlds[2][32 * 64];  // 8 KB
  __shared__ __attribute__((aligned(16))) unsigned short x0s[16][16 * 40];  // 20 KB

  const int tid  = threadIdx.x;
  const int lane = tid & 63;
  const int wv   = tid >> 6;
  const int q    = lane >> 4;
  const int col  = lane & 15;
  const int hq   = blockIdx.x & 3;
  const int bblk = (blockIdx.x >> 2) * 16;
  const int bwave = bblk + wv * 4;

  // ---- stage X0 (bf16) into LDS: x0s[bi][d*40 + j] ----
  {
    const int bi = tid >> 4, d = tid & 15;
    const unsigned short* src = X0T + ((size_t)(bblk + bi) * 16 + d) * 64;
    unsigned short* dst = &x0s[bi][d * 40];
#pragma unroll
    for (int j4 = 0; j4 < 40; j4 += 4)
      *(ushort4*)&dst[j4] = *(const ushort4*)&src[j4];
  }

  // ---- W staging: 4 KB/stage, 16 B/thread VGPR bounce ----
  // thread t stages LDS bytes [t*16, t*16+16) = row (t>>3) of 32, chunk (t&7)
  const char* gbase = (const char*)Wp +
      ((size_t)(hq * 32 + (tid >> 3)) * FI_PAD) * 2 + (tid & 7) * 16;

  auto gload = [&](int s) -> uint4 {
    const int kp = (KPASS == 2 && s >= NB_F0) ? 1 : 0;
    const int j = s - kp * NB_F0;
    return *(const uint4*)(gbase + (size_t)j * (NB_H * FI_PAD * 2) + kp * 128);
  };
  auto sstore = [&](int buf, uint4 v) {
    *(uint4*)((char*)&Wlds[buf][0] + tid * 16) = v;   // typed: 4096 B per buffer
  };

  // ---- B fragments for current 64-wide K window ----
  s16x8 bf[4][2];
  auto load_bf = [&](int kp) {
#pragma unroll
    for (int bi = 0; bi < 4; ++bi)
#pragma unroll
      for (int kc = 0; kc < 2; ++kc)
        bf[bi][kc] = *(const s16x8*)(XiT +
            ((size_t)(bwave + bi) * 16 + col) * FI_PAD + kp * 64 + kc * 32 + q * 8);
  };
  load_bf(0);

  f32x4 Xacc[2][4];  // [ht][bi]
#pragma unroll
  for (int ht = 0; ht < 2; ++ht)
#pragma unroll
    for (int bi = 0; bi < 4; ++bi) Xacc[ht][bi] = f32x4{0.f, 0.f, 0.f, 0.f};

  uint4 stg = gload(0);
  sstore(0, stg);
  if (S > 1) stg = gload(1);

#pragma unroll 2
  for (int s = 0; s < S; ++s) {
    __syncthreads();                 // buf[s&1] staged & all waves past prior reads

    const int j = (KPASS == 2 && s >= NB_F0) ? s - NB_F0 : s;
    const unsigned short* wb = &Wlds[s & 1][0];

    float x0v[4];
#pragma unroll
    for (int bi = 0; bi < 4; ++bi)
      x0v[bi] = bf16_to_f32(x0s[wv * 4 + bi][col * 40 + j]);

#pragma unroll
    for (int ht = 0; ht < 2; ++ht) {
      f32x4 y[4];
#pragma unroll
      for (int bi = 0; bi < 4; ++bi) y[bi] = f32x4{0.f, 0.f, 0.f, 0.f};
#pragma unroll
      for (int kc = 0; kc < 2; ++kc) {
        const s16x8 af = *(const s16x8*)&wb[(ht * 16 + col) * 64 +
                                            (((kc * 4 + q) ^ (col & 7)) << 3)];
#pragma unroll
        for (int bi = 0; bi < 4; ++bi)
          y[bi] = __builtin_amdgcn_mfma_f32_16x16x32_bf16(af, bf[bi][kc], y[bi],
                                                          0, 0, 0);
      }
#pragma unroll
      for (int bi = 0; bi < 4; ++bi)
#pragma unroll
        for (int r = 0; r < 4; ++r) Xacc[ht][bi][r] += x0v[bi] * y[bi][r];
    }

    // stage s+1 into the other buffer; next barrier publishes it.
    // Safe: every wave is past the stage-s barrier, so none still reads it.
    if (s + 1 < S) {
      sstore((s + 1) & 1, stg);
      if (s + 2 < S) stg = gload(s + 2);
    }
    if (KPASS == 2 && s == NB_F0 - 1) load_bf(1);  // WAR on bf; compiler orders
  }

  // ---- epilogue: bias, optional bf16 store of Xn, d-reduction to output ----
#pragma unroll
  for (int ht = 0; ht < 2; ++ht) {
    const int hbase = hq * 32 + ht * 16 + q * 4;
    const float* bp = bias + hbase;
    float b4[4] = {bp[0], bp[1], bp[2], bp[3]};
#pragma unroll
    for (int bi = 0; bi < 4; ++bi) {
      const int b = bwave + bi;
      float v[4];
#pragma unroll
      for (int r = 0; r < 4; ++r) v[r] = Xacc[ht][bi][r] + b4[r];
      if (STORE_XN) {
        ushort4 pk;
        pk.x = rne_bf16(v[0]); pk.y = rne_bf16(v[1]);
        pk.z = rne_bf16(v[2]); pk.w = rne_bf16(v[3]);
        *(ushort4*)&XnT[((size_t)b * 16 + col) * NB_H + hbase] = pk;
      }
#pragma unroll
      for (int m = 1; m < 16; m <<= 1)
#pragma unroll
        for (int r = 0; r < 4; ++r) v[r] += __shfl_xor(v[r], m);
      if (col == 0) {
        float4 o; o.x = v[0]; o.y = v[1]; o.z = v[2]; o.w = v[3];
        *(float4*)&outp[(size_t)b * 384 + hbase] = o;
      }
    }
  }
}

extern "C" void kernel_launch(void* const* d_in, const int* in_sizes, int n_in,
                              void* d_out, int out_size, void* d_ws, size_t ws_size,
                              hipStream_t stream) {
  (void)in_sizes; (void)n_in; (void)out_size; (void)ws_size;
  const float* X0g = (const float*)d_in[0];
  const float* W0  = (const float*)d_in[1];
  const float* b0  = (const float*)d_in[2];
  const float* W1  = (const float*)d_in[3];
  const float* b1  = (const float*)d_in[4];
  const float* W2  = (const float*)d_in[5];
  const float* b2  = (const float*)d_in[6];
  float* out = (float*)d_out;

  char* p = (char*)d_ws;
  unsigned short* X0T = (unsigned short*)p; p += (size_t)NB_B * 16 * 64 * 2;
  unsigned short* X1T = (unsigned short*)p; p += (size_t)NB_B * 16 * 128 * 2;
  unsigned short* X2T = (unsigned short*)p; p += (size_t)NB_B * 16 * 128 * 2;
  unsigned short* Wp0 = (unsigned short*)p; p += (size_t)NB_F0 * 128 * 64 * 2;
  unsigned short* Wp1 = (unsigned short*)p; p += (size_t)NB_F0 * 128 * 128 * 2;
  unsigned short* Wp2 = (unsigned short*)p; p += (size_t)NB_F0 * 128 * 128 * 2;

  hipLaunchKernelGGL(prep_x0_kernel, dim3(NB_B), dim3(256), 0, stream, X0g, X0T);
  const int tw0  = NB_F0 * 128 * 64;
  const int tw12 = NB_F0 * 128 * 128;
  hipLaunchKernelGGL(prep_w_kernel, dim3((tw0 + 255) / 256), dim3(256), 0, stream,
                     W0, Wp0, 39, 64, tw0);
  hipLaunchKernelGGL(prep_w_kernel, dim3((tw12 + 255) / 256), dim3(256), 0, stream,
                     W1, Wp1, 128, 128, tw12);
  hipLaunchKernelGGL(prep_w_kernel, dim3((tw12 + 255) / 256), dim3(256), 0, stream,
                     W2, Wp2, 128, 128, tw12);

  hipLaunchKernelGGL((cin_layer<64, true>),   dim3(1024), dim3(256), 0, stream,
                     Wp0, X0T, X0T, b0, X1T, out + 0);
  hipLaunchKernelGGL((cin_layer<128, true>),  dim3(1024), dim3(256), 0, stream,
                     Wp1, X1T, X0T, b1, X2T, out + 128);
  hipLaunchKernelGGL((cin_layer<128, false>), dim3(1024), dim3(256), 0, stream,
                     Wp2, X2T, X0T, b2, (unsigned short*)nullptr, out + 256);
}

// Round 5
// 968.654 us; speedup vs baseline: 1.6036x; 1.6036x over previous
//
#include <hip/hip_runtime.h>
#include <stdint.h>

// CIN layers: Xn[b,h,d] = sum_{j,k} W[h,j,k] * X0[b,j,d] * Xi[b,k,d] + bias[h]
// Factored:   y[d,h]    = sum_k Xi[b,k,d] * W[h,j,k]  (MFMA: A=Xi (m=d), B=W (n=h))
//             Xn[b,h,d] = sum_j X0[b,j,d] * y + bias   (f32 FMA on C rows = d)
// Barrier-free K-loop: W streamed from global in fragment-linear layout (2
// coalesced dwordx4/stage, double-buffered in regs); Xi fragments resident in
// regs; only x0 factors come from LDS (20 KB/block).
// Grid: 2048 blocks = 256 b-groups x 8 h-tiles; block = 4 waves x 4 b x 16 h.
// R4 failure: launch_bounds(256,4) + ~140 live VGPRs -> massive scratch spill
// (2.5 GB HBM/dispatch). This design needs ~105 regs -> fits the 128 cap.

#define NB_F0 39
#define NB_H  128
#define NB_B  4096

typedef float f32x4 __attribute__((ext_vector_type(4)));
typedef short s16x8 __attribute__((ext_vector_type(8)));

__device__ __forceinline__ unsigned short rne_bf16(float f) {
  union { float f; unsigned u; } v; v.f = f;
  return (unsigned short)((v.u + 0x7fffu + ((v.u >> 16) & 1u)) >> 16);
}
__device__ __forceinline__ float bf16_to_f32(unsigned short s) {
  union { unsigned u; float f; } v; v.u = ((unsigned)s) << 16;
  return v.f;
}

// X0 f32 [B][39][16] -> X0T bf16 [B][16][64] (A-fragment layout, j-padded)
//                    -> X0c bf16 [B][39][16] (plain cast, for x0s staging)
__global__ void prep_x0_kernel(const float* __restrict__ X0g,
                               unsigned short* __restrict__ X0T,
                               unsigned short* __restrict__ X0c) {
  const int b = blockIdx.x;
  const int t = threadIdx.x;
  {
    const int d  = t >> 4;
    const int k4 = (t & 15) << 2;
    unsigned short vv[4];
#pragma unroll
    for (int i = 0; i < 4; ++i) {
      const int k = k4 + i;
      vv[i] = (k < NB_F0) ? rne_bf16(X0g[(size_t)b * (NB_F0 * 16) + k * 16 + d])
                          : (unsigned short)0;
    }
    ushort4 pk; pk.x = vv[0]; pk.y = vv[1]; pk.z = vv[2]; pk.w = vv[3];
    *(ushort4*)&X0T[((size_t)b * 16 + d) * 64 + k4] = pk;
  }
  for (int idx = t; idx < NB_F0 * 16; idx += 256)
    X0c[(size_t)b * (NB_F0 * 16) + idx] =
        rne_bf16(X0g[(size_t)b * (NB_F0 * 16) + idx]);
}

// W f32 [128][39*Fi] -> Wf bf16 fragment-linear:
//   Wf[(((j*8 + t)*KCT + kct)*64 + lane)*8 + i] = W[h=t*16+(lane&15)]
//                                                  [j, k=kct*32+(lane>>4)*8+i]
// (zero-padded k>=Fi). One (j,t,kct) unit = 1024 B = one wave dwordx4 load.
__global__ void prep_w_kernel(const float* __restrict__ Wsrc,
                              unsigned short* __restrict__ Wdst,
                              int Fi, int kshift, int total) {
  int idx = blockIdx.x * 256 + threadIdx.x;
  if (idx >= total) return;
  const int i    = idx & 7;
  const int lane = (idx >> 3) & 63;
  const int kct  = (idx >> 9) & ((1 << kshift) - 1);
  const int jt   = idx >> (9 + kshift);
  const int t    = jt & 7;
  const int j    = jt >> 3;
  const int h = t * 16 + (lane & 15);
  const int k = kct * 32 + (lane >> 4) * 8 + i;
  unsigned short v = 0;
  if (k < Fi) v = rne_bf16(Wsrc[(size_t)h * (NB_F0 * Fi) + j * Fi + k]);
  Wdst[idx] = v;
}

template <int FI_PAD, bool STORE_XN>
__global__ __launch_bounds__(256, 4) void cin_layer(
    const unsigned short* __restrict__ Wf,   // fragment-linear W (see prep)
    const unsigned short* __restrict__ XiT,  // [B][16][FI_PAD] bf16
    const unsigned short* __restrict__ X0c,  // [B][39][16] bf16
    const float* __restrict__ bias,          // [128]
    unsigned short* __restrict__ XnT,        // [B][16][128] bf16 (or unused)
    float* __restrict__ outp)                // d_out + layer*128, stride 384
{
  constexpr int KPASS = FI_PAD / 64;   // 1 or 2 K-passes of 64
  constexpr int KCT   = FI_PAD / 32;   // total 32-wide k-chunks
  constexpr int S     = NB_F0 * KPASS;

  __shared__ __attribute__((aligned(16))) unsigned short x0s[16 * NB_F0 * 16];

  const int tid  = threadIdx.x;
  const int lane = tid & 63;
  const int wv   = tid >> 6;
  const int q    = lane >> 4;
  const int col  = lane & 15;
  const int ht   = blockIdx.x & 7;
  const int bblk = (blockIdx.x >> 3) * 16;
  const int bwave = bblk + wv * 4;

  // ---- stage x0 factors (flat copy, coalesced) ----
  {
    const unsigned short* src = X0c + (size_t)bblk * (NB_F0 * 16);
    for (int c = tid; c < (16 * NB_F0 * 16) / 8; c += 256)
      *(s16x8*)&x0s[c * 8] = *(const s16x8*)&src[c * 8];
  }
  __syncthreads();  // only barrier in the kernel

  // ---- Xi A-fragments: A[m=d=col][k=q*8+i], resident in regs ----
  s16x8 af[4][2];
  auto load_af = [&](int pass) {
#pragma unroll
    for (int bi = 0; bi < 4; ++bi)
#pragma unroll
      for (int kc = 0; kc < 2; ++kc)
        af[bi][kc] = *(const s16x8*)(XiT +
            ((size_t)(bwave + bi) * 16 + col) * FI_PAD + pass * 64 + kc * 32 + q * 8);
  };
  load_af(0);

  // ---- W B-fragment stream: B[k=q*8+i][n=h=col] ----
  const unsigned short* wbase = Wf + ((size_t)ht * KCT) * 512 + lane * 8;
  auto wload = [&](int s, s16x8* dst) {
    const int pass = (KPASS == 2 && s >= NB_F0) ? 1 : 0;
    const int j = s - pass * NB_F0;
    const unsigned short* p = wbase + ((size_t)j * 8 * KCT + pass * 2) * 512;
    dst[0] = *(const s16x8*)p;
    dst[1] = *(const s16x8*)(p + 512);
  };

  f32x4 Xacc[4];
#pragma unroll
  for (int bi = 0; bi < 4; ++bi) Xacc[bi] = f32x4{0.f, 0.f, 0.f, 0.f};

  s16x8 wf[2][2];
  wload(0, wf[0]);

#pragma unroll 2
  for (int s = 0; s < S; ++s) {
    if (s + 1 < S) wload(s + 1, wf[(s + 1) & 1]);  // prefetch next stage

    const int j = (KPASS == 2 && s >= NB_F0) ? s - NB_F0 : s;

    float x0v[4][4];
#pragma unroll
    for (int bi = 0; bi < 4; ++bi) {
      const ushort4 u =
          *(const ushort4*)&x0s[(((wv * 4 + bi) * NB_F0) + j) * 16 + q * 4];
      x0v[bi][0] = bf16_to_f32(u.x); x0v[bi][1] = bf16_to_f32(u.y);
      x0v[bi][2] = bf16_to_f32(u.z); x0v[bi][3] = bf16_to_f32(u.w);
    }

    f32x4 y[4];
#pragma unroll
    for (int bi = 0; bi < 4; ++bi) y[bi] = f32x4{0.f, 0.f, 0.f, 0.f};
#pragma unroll
    for (int kc = 0; kc < 2; ++kc)
#pragma unroll
      for (int bi = 0; bi < 4; ++bi)
        y[bi] = __builtin_amdgcn_mfma_f32_16x16x32_bf16(af[bi][kc], wf[s & 1][kc],
                                                        y[bi], 0, 0, 0);
#pragma unroll
    for (int bi = 0; bi < 4; ++bi)
#pragma unroll
      for (int r = 0; r < 4; ++r) Xacc[bi][r] += x0v[bi][r] * y[bi][r];

    if (KPASS == 2 && s == NB_F0 - 1) load_af(1);  // second 64-wide K window
  }

  // ---- epilogue: bias, optional Xn store, d-reduction (in-lane r + q-shuffles) ----
  const float bias_v = bias[ht * 16 + col];
#pragma unroll
  for (int bi = 0; bi < 4; ++bi) {
    const int b = bwave + bi;
    float v[4];
#pragma unroll
    for (int r = 0; r < 4; ++r) v[r] = Xacc[bi][r] + bias_v;
    if (STORE_XN) {
#pragma unroll
      for (int r = 0; r < 4; ++r)
        XnT[((size_t)b * 16 + q * 4 + r) * NB_H + ht * 16 + col] = rne_bf16(v[r]);
    }
    float tot = (v[0] + v[1]) + (v[2] + v[3]);
    tot += __shfl_xor(tot, 16);
    tot += __shfl_xor(tot, 32);
    if (q == 0) outp[(size_t)b * 384 + ht * 16 + col] = tot;
  }
}

extern "C" void kernel_launch(void* const* d_in, const int* in_sizes, int n_in,
                              void* d_out, int out_size, void* d_ws, size_t ws_size,
                              hipStream_t stream) {
  (void)in_sizes; (void)n_in; (void)out_size; (void)ws_size;
  const float* X0g = (const float*)d_in[0];
  const float* W0  = (const float*)d_in[1];
  const float* b0  = (const float*)d_in[2];
  const float* W1  = (const float*)d_in[3];
  const float* b1  = (const float*)d_in[4];
  const float* W2  = (const float*)d_in[5];
  const float* b2  = (const float*)d_in[6];
  float* out = (float*)d_out;

  char* p = (char*)d_ws;
  unsigned short* X0T = (unsigned short*)p; p += (size_t)NB_B * 16 * 64 * 2;
  unsigned short* X0c = (unsigned short*)p; p += (size_t)NB_B * NB_F0 * 16 * 2;
  unsigned short* X1T = (unsigned short*)p; p += (size_t)NB_B * 16 * 128 * 2;
  unsigned short* X2T = (unsigned short*)p; p += (size_t)NB_B * 16 * 128 * 2;
  unsigned short* Wf0 = (unsigned short*)p; p += (size_t)NB_F0 * 8 * 2 * 512 * 2;
  unsigned short* Wf1 = (unsigned short*)p; p += (size_t)NB_F0 * 8 * 4 * 512 * 2;
  unsigned short* Wf2 = (unsigned short*)p; p += (size_t)NB_F0 * 8 * 4 * 512 * 2;

  hipLaunchKernelGGL(prep_x0_kernel, dim3(NB_B), dim3(256), 0, stream,
                     X0g, X0T, X0c);
  const int tw0  = NB_F0 * 8 * 2 * 512;   // KCT=2
  const int tw12 = NB_F0 * 8 * 4 * 512;   // KCT=4
  hipLaunchKernelGGL(prep_w_kernel, dim3((tw0 + 255) / 256), dim3(256), 0, stream,
                     W0, Wf0, 39, 1, tw0);
  hipLaunchKernelGGL(prep_w_kernel, dim3((tw12 + 255) / 256), dim3(256), 0, stream,
                     W1, Wf1, 128, 2, tw12);
  hipLaunchKernelGGL(prep_w_kernel, dim3((tw12 + 255) / 256), dim3(256), 0, stream,
                     W2, Wf2, 128, 2, tw12);

  hipLaunchKernelGGL((cin_layer<64, true>),   dim3(2048), dim3(256), 0, stream,
                     Wf0, X0T, X0c, b0, X1T, out + 0);
  hipLaunchKernelGGL((cin_layer<128, true>),  dim3(2048), dim3(256), 0, stream,
                     Wf1, X1T, X0c, b1, X2T, out + 128);
  hipLaunchKernelGGL((cin_layer<128, false>), dim3(2048), dim3(256), 0, stream,
                     Wf2, X2T, X0c, b2, (unsigned short*)nullptr, out + 256);
}

// Round 6
// 358.153 us; speedup vs baseline: 4.3371x; 2.7046x over previous
//
#include <hip/hip_runtime.h>
#include <stdint.h>

// CIN layers: Xn[b,h,d] = sum_{j,k} W[h,j,k] * X0[b,j,d] * Xi[b,k,d] + bias[h]
// Factored:   y[d,h]    = sum_k Xi[b,k,d] * W[h,j,k]  (MFMA: A=Xi (m=d), B=W (n=h))
//             Xn[b,h,d] = sum_j X0[b,j,d] * y + bias   (f32 FMA on C rows = d)
// Barrier-free K-loop: W streamed from global in fragment-linear layout,
// double-buffered in named regs (manual 2-stage unroll + odd tail); Xi
// fragments resident in regs; only x0 factors come from LDS (10 KB/block).
// Grid: 4096 blocks = 512 b-groups x 8 h-tiles; block = 4 waves x 2 b x 16 h.
// R4/R5 failure mode: register cliff under launch_bounds(256,4) -> instantiation-
// dependent scratch spill (GBs of HBM). Fix: nb=2 (~85 live regs) + (256,3)
// (170-reg cap) + no pragma-unroll parity buffers. Spill impossible with margin.

#define NB_F0 39
#define NB_H  128
#define NB_B  4096

typedef float f32x4 __attribute__((ext_vector_type(4)));
typedef short s16x8 __attribute__((ext_vector_type(8)));

__device__ __forceinline__ unsigned short rne_bf16(float f) {
  union { float f; unsigned u; } v; v.f = f;
  return (unsigned short)((v.u + 0x7fffu + ((v.u >> 16) & 1u)) >> 16);
}
__device__ __forceinline__ float bf16_to_f32(unsigned short s) {
  union { unsigned u; float f; } v; v.u = ((unsigned)s) << 16;
  return v.f;
}

// X0 f32 [B][39][16] -> X0T bf16 [B][16][64] (A-fragment layout, j-padded)
//                    -> X0c bf16 [B][39][16] (plain cast, for x0s staging)
__global__ void prep_x0_kernel(const float* __restrict__ X0g,
                               unsigned short* __restrict__ X0T,
                               unsigned short* __restrict__ X0c) {
  const int b = blockIdx.x;
  const int t = threadIdx.x;
  {
    const int d  = t >> 4;
    const int k4 = (t & 15) << 2;
    unsigned short vv[4];
#pragma unroll
    for (int i = 0; i < 4; ++i) {
      const int k = k4 + i;
      vv[i] = (k < NB_F0) ? rne_bf16(X0g[(size_t)b * (NB_F0 * 16) + k * 16 + d])
                          : (unsigned short)0;
    }
    ushort4 pk; pk.x = vv[0]; pk.y = vv[1]; pk.z = vv[2]; pk.w = vv[3];
    *(ushort4*)&X0T[((size_t)b * 16 + d) * 64 + k4] = pk;
  }
  for (int idx = t; idx < NB_F0 * 16; idx += 256)
    X0c[(size_t)b * (NB_F0 * 16) + idx] =
        rne_bf16(X0g[(size_t)b * (NB_F0 * 16) + idx]);
}

// W f32 [128][39*Fi] -> Wf bf16 fragment-linear:
//   Wf[(((j*8 + t)*KCT + kct)*64 + lane)*8 + i] = W[h=t*16+(lane&15)]
//                                                  [j, k=kct*32+(lane>>4)*8+i]
// (zero-padded k>=Fi). One (j,t,kct) unit = 1024 B = one wave dwordx4 load.
__global__ void prep_w_kernel(const float* __restrict__ Wsrc,
                              unsigned short* __restrict__ Wdst,
                              int Fi, int kshift, int total) {
  int idx = blockIdx.x * 256 + threadIdx.x;
  if (idx >= total) return;
  const int i    = idx & 7;
  const int lane = (idx >> 3) & 63;
  const int kct  = (idx >> 9) & ((1 << kshift) - 1);
  const int jt   = idx >> (9 + kshift);
  const int t    = jt & 7;
  const int j    = jt >> 3;
  const int h = t * 16 + (lane & 15);
  const int k = kct * 32 + (lane >> 4) * 8 + i;
  unsigned short v = 0;
  if (k < Fi) v = rne_bf16(Wsrc[(size_t)h * (NB_F0 * Fi) + j * Fi + k]);
  Wdst[idx] = v;
}

template <int FI_PAD, bool STORE_XN>
__global__ __launch_bounds__(256, 3) void cin_layer(
    const unsigned short* __restrict__ Wf,   // fragment-linear W (see prep)
    const unsigned short* __restrict__ XiT,  // [B][16][FI_PAD] bf16
    const unsigned short* __restrict__ X0c,  // [B][39][16] bf16
    const float* __restrict__ bias,          // [128]
    unsigned short* __restrict__ XnT,        // [B][16][128] bf16 (or unused)
    float* __restrict__ outp)                // d_out + layer*128, stride 384
{
  constexpr int KPASS = FI_PAD / 64;   // 1 or 2 K-passes of 64
  constexpr int KCT   = FI_PAD / 32;   // total 32-wide k-chunks
  constexpr int S     = NB_F0 * KPASS;

  __shared__ __attribute__((aligned(16))) unsigned short x0s[8 * NB_F0 * 16];

  const int tid  = threadIdx.x;
  const int lane = tid & 63;
  const int wv   = tid >> 6;
  const int q    = lane >> 4;
  const int col  = lane & 15;
  const int ht   = blockIdx.x & 7;
  const int bblk = (blockIdx.x >> 3) * 8;
  const int bwave = bblk + wv * 2;

  // ---- stage x0 factors (flat copy, coalesced; 4992 shorts) ----
  {
    const unsigned short* src = X0c + (size_t)bblk * (NB_F0 * 16);
    for (int c = tid; c < (8 * NB_F0 * 16) / 8; c += 256)
      *(s16x8*)&x0s[c * 8] = *(const s16x8*)&src[c * 8];
  }
  __syncthreads();  // only barrier in the kernel

  // ---- Xi A-fragments: A[m=d=col][k=q*8+i], resident in regs ----
  s16x8 af[2][2];
  auto load_af = [&](int pass) {
#pragma unroll
    for (int bi = 0; bi < 2; ++bi)
#pragma unroll
      for (int kc = 0; kc < 2; ++kc)
        af[bi][kc] = *(const s16x8*)(XiT +
            ((size_t)(bwave + bi) * 16 + col) * FI_PAD + pass * 64 + kc * 32 + q * 8);
  };
  load_af(0);

  // ---- W B-fragment stream: B[k=q*8+i][n=h=col] ----
  const unsigned short* wbase = Wf + ((size_t)ht * KCT) * 512 + lane * 8;
  auto wload = [&](int s, s16x8* dst) {
    const int pass = (KPASS == 2 && s >= NB_F0) ? 1 : 0;
    const int j = s - pass * NB_F0;
    const unsigned short* p = wbase + ((size_t)j * 8 * KCT + pass * 2) * 512;
    dst[0] = *(const s16x8*)p;
    dst[1] = *(const s16x8*)(p + 512);
  };

  f32x4 Xacc[2];
  Xacc[0] = f32x4{0.f, 0.f, 0.f, 0.f};
  Xacc[1] = f32x4{0.f, 0.f, 0.f, 0.f};

  auto stage = [&](int s, const s16x8* wfr) {
    const int j = (KPASS == 2 && s >= NB_F0) ? s - NB_F0 : s;
    f32x4 y[2];
    y[0] = f32x4{0.f, 0.f, 0.f, 0.f};
    y[1] = f32x4{0.f, 0.f, 0.f, 0.f};
#pragma unroll
    for (int kc = 0; kc < 2; ++kc)
#pragma unroll
      for (int bi = 0; bi < 2; ++bi)
        y[bi] = __builtin_amdgcn_mfma_f32_16x16x32_bf16(af[bi][kc], wfr[kc],
                                                        y[bi], 0, 0, 0);
#pragma unroll
    for (int bi = 0; bi < 2; ++bi) {
      const ushort4 u =
          *(const ushort4*)&x0s[(((wv * 2 + bi) * NB_F0) + j) * 16 + q * 4];
      Xacc[bi][0] += bf16_to_f32(u.x) * y[bi][0];
      Xacc[bi][1] += bf16_to_f32(u.y) * y[bi][1];
      Xacc[bi][2] += bf16_to_f32(u.z) * y[bi][2];
      Xacc[bi][3] += bf16_to_f32(u.w) * y[bi][3];
    }
  };

  s16x8 wf0[2], wf1[2];
  wload(0, wf0);
  for (int s = 0; s + 1 < S; s += 2) {
    wload(s + 1, wf1);
    stage(s, wf0);
    if (s + 2 < S) wload(s + 2, wf0);
    if (KPASS == 2 && s + 1 == NB_F0) load_af(1);  // K-window switch (odd NB_F0)
    stage(s + 1, wf1);
  }
  if (S & 1) stage(S - 1, wf0);

  // ---- epilogue: bias, optional Xn store, d-reduction (in-lane r + q-shuffles) ----
  const float bias_v = bias[ht * 16 + col];
#pragma unroll
  for (int bi = 0; bi < 2; ++bi) {
    const int b = bwave + bi;
    float v[4];
#pragma unroll
    for (int r = 0; r < 4; ++r) v[r] = Xacc[bi][r] + bias_v;
    if (STORE_XN) {
#pragma unroll
      for (int r = 0; r < 4; ++r)
        XnT[((size_t)b * 16 + q * 4 + r) * NB_H + ht * 16 + col] = rne_bf16(v[r]);
    }
    float tot = (v[0] + v[1]) + (v[2] + v[3]);
    tot += __shfl_xor(tot, 16);
    tot += __shfl_xor(tot, 32);
    if (q == 0) outp[(size_t)b * 384 + ht * 16 + col] = tot;
  }
}

extern "C" void kernel_launch(void* const* d_in, const int* in_sizes, int n_in,
                              void* d_out, int out_size, void* d_ws, size_t ws_size,
                              hipStream_t stream) {
  (void)in_sizes; (void)n_in; (void)out_size; (void)ws_size;
  const float* X0g = (const float*)d_in[0];
  const float* W0  = (const float*)d_in[1];
  const float* b0  = (const float*)d_in[2];
  const float* W1  = (const float*)d_in[3];
  const float* b1  = (const float*)d_in[4];
  const float* W2  = (const float*)d_in[5];
  const float* b2  = (const float*)d_in[6];
  float* out = (float*)d_out;

  char* p = (char*)d_ws;
  unsigned short* X0T = (unsigned short*)p; p += (size_t)NB_B * 16 * 64 * 2;
  unsigned short* X0c = (unsigned short*)p; p += (size_t)NB_B * NB_F0 * 16 * 2;
  unsigned short* X1T = (unsigned short*)p; p += (size_t)NB_B * 16 * 128 * 2;
  unsigned short* X2T = (unsigned short*)p; p += (size_t)NB_B * 16 * 128 * 2;
  unsigned short* Wf0 = (unsigned short*)p; p += (size_t)NB_F0 * 8 * 2 * 512 * 2;
  unsigned short* Wf1 = (unsigned short*)p; p += (size_t)NB_F0 * 8 * 4 * 512 * 2;
  unsigned short* Wf2 = (unsigned short*)p; p += (size_t)NB_F0 * 8 * 4 * 512 * 2;

  hipLaunchKernelGGL(prep_x0_kernel, dim3(NB_B), dim3(256), 0, stream,
                     X0g, X0T, X0c);
  const int tw0  = NB_F0 * 8 * 2 * 512;   // KCT=2
  const int tw12 = NB_F0 * 8 * 4 * 512;   // KCT=4
  hipLaunchKernelGGL(prep_w_kernel, dim3((tw0 + 255) / 256), dim3(256), 0, stream,
                     W0, Wf0, 39, 1, tw0);
  hipLaunchKernelGGL(prep_w_kernel, dim3((tw12 + 255) / 256), dim3(256), 0, stream,
                     W1, Wf1, 128, 2, tw12);
  hipLaunchKernelGGL(prep_w_kernel, dim3((tw12 + 255) / 256), dim3(256), 0, stream,
                     W2, Wf2, 128, 2, tw12);

  hipLaunchKernelGGL((cin_layer<64, true>),   dim3(4096), dim3(256), 0, stream,
                     Wf0, X0T, X0c, b0, X1T, out + 0);
  hipLaunchKernelGGL((cin_layer<128, true>),  dim3(4096), dim3(256), 0, stream,
                     Wf1, X1T, X0c, b1, X2T, out + 128);
  hipLaunchKernelGGL((cin_layer<128, false>), dim3(4096), dim3(256), 0, stream,
                     Wf2, X2T, X0c, b2, (unsigned short*)nullptr, out + 256);
}

// Round 7
// 350.230 us; speedup vs baseline: 4.4352x; 1.0226x over previous
//
#include <hip/hip_runtime.h>
#include <stdint.h>

// CIN layers: Xn[b,h,d] = sum_{j,k} W[h,j,k] * X0[b,j,d] * Xi[b,k,d] + bias[h]
// Factored:   y[d,h]    = sum_k Xi[b,k,d] * W[h,j,k]  (MFMA: A=Xi (m=d), B=W (n=h))
//             Xn[b,h,d] = sum_j X0[b,j,d] * y + bias   (f32 FMA on C rows = d)
// Barrier-free K-loop: W streamed from global in fragment-linear layout.
// R6 -> R7: K-loop was memory-LATENCY bound (all 3 layers ~120us regardless of
// MFMA count; VALUBusy 48% at 4.6 waves/SIMD). Fixes:
//  (1) wf prefetch ring depth 4 (distance-3 ~= 250 cyc, covers L2 latency;
//      named buffers + constexpr tail -> no dynamic reg indexing).
//  (2) XCD swizzle: bgroup = blockIdx&511, ht = blockIdx>>9 so XCD i
//      (= blockIdx%8 round-robin) owns b-groups === i (mod 8): per-XCD XiT
//      slice 2.1MB + Wf 1.3MB fits 4MB L2 -> ht re-reads hit L2 not L3/HBM.
// Grid: 4096 blocks = 512 b-groups x 8 h-tiles; block = 4 waves x 2 b x 16 h.

#define NB_F0 39
#define NB_H  128
#define NB_B  4096

typedef float f32x4 __attribute__((ext_vector_type(4)));
typedef short s16x8 __attribute__((ext_vector_type(8)));

__device__ __forceinline__ unsigned short rne_bf16(float f) {
  union { float f; unsigned u; } v; v.f = f;
  return (unsigned short)((v.u + 0x7fffu + ((v.u >> 16) & 1u)) >> 16);
}
__device__ __forceinline__ float bf16_to_f32(unsigned short s) {
  union { unsigned u; float f; } v; v.u = ((unsigned)s) << 16;
  return v.f;
}

// X0 f32 [B][39][16] -> X0T bf16 [B][16][64] (A-fragment layout, j-padded)
//                    -> X0c bf16 [B][39][16] (plain cast, for x0s staging)
__global__ void prep_x0_kernel(const float* __restrict__ X0g,
                               unsigned short* __restrict__ X0T,
                               unsigned short* __restrict__ X0c) {
  const int b = blockIdx.x;
  const int t = threadIdx.x;
  {
    const int d  = t >> 4;
    const int k4 = (t & 15) << 2;
    unsigned short vv[4];
#pragma unroll
    for (int i = 0; i < 4; ++i) {
      const int k = k4 + i;
      vv[i] = (k < NB_F0) ? rne_bf16(X0g[(size_t)b * (NB_F0 * 16) + k * 16 + d])
                          : (unsigned short)0;
    }
    ushort4 pk; pk.x = vv[0]; pk.y = vv[1]; pk.z = vv[2]; pk.w = vv[3];
    *(ushort4*)&X0T[((size_t)b * 16 + d) * 64 + k4] = pk;
  }
  for (int idx = t; idx < NB_F0 * 16; idx += 256)
    X0c[(size_t)b * (NB_F0 * 16) + idx] =
        rne_bf16(X0g[(size_t)b * (NB_F0 * 16) + idx]);
}

// W f32 [128][39*Fi] -> Wf bf16 fragment-linear:
//   Wf[(((j*8 + t)*KCT + kct)*64 + lane)*8 + i] = W[h=t*16+(lane&15)]
//                                                  [j, k=kct*32+(lane>>4)*8+i]
// (zero-padded k>=Fi). One (j,t,kct) unit = 1024 B = one wave dwordx4 load.
__global__ void prep_w_kernel(const float* __restrict__ Wsrc,
                              unsigned short* __restrict__ Wdst,
                              int Fi, int kshift, int total) {
  int idx = blockIdx.x * 256 + threadIdx.x;
  if (idx >= total) return;
  const int i    = idx & 7;
  const int lane = (idx >> 3) & 63;
  const int kct  = (idx >> 9) & ((1 << kshift) - 1);
  const int jt   = idx >> (9 + kshift);
  const int t    = jt & 7;
  const int j    = jt >> 3;
  const int h = t * 16 + (lane & 15);
  const int k = kct * 32 + (lane >> 4) * 8 + i;
  unsigned short v = 0;
  if (k < Fi) v = rne_bf16(Wsrc[(size_t)h * (NB_F0 * Fi) + j * Fi + k]);
  Wdst[idx] = v;
}

template <int FI_PAD, bool STORE_XN>
__global__ __launch_bounds__(256, 3) void cin_layer(
    const unsigned short* __restrict__ Wf,   // fragment-linear W (see prep)
    const unsigned short* __restrict__ XiT,  // [B][16][FI_PAD] bf16
    const unsigned short* __restrict__ X0c,  // [B][39][16] bf16
    const float* __restrict__ bias,          // [128]
    unsigned short* __restrict__ XnT,        // [B][16][128] bf16 (or unused)
    float* __restrict__ outp)                // d_out + layer*128, stride 384
{
  constexpr int KPASS = FI_PAD / 64;   // 1 or 2 K-passes of 64
  constexpr int KCT   = FI_PAD / 32;   // total 32-wide k-chunks
  constexpr int S     = NB_F0 * KPASS;

  __shared__ __attribute__((aligned(16))) unsigned short x0s[8 * NB_F0 * 16];

  const int tid  = threadIdx.x;
  const int lane = tid & 63;
  const int wv   = tid >> 6;
  const int q    = lane >> 4;
  const int col  = lane & 15;
  // XCD swizzle: low 9 bits = b-group (so blockIdx%8 == bgroup%8 == XCD id),
  // high 3 bits = h-tile. Same-XiT blocks share an XCD -> XiT slice L2-resident.
  const int ht   = blockIdx.x >> 9;
  const int bblk = (blockIdx.x & 511) * 8;
  const int bwave = bblk + wv * 2;

  // ---- stage x0 factors (flat copy, coalesced; 4992 shorts) ----
  {
    const unsigned short* src = X0c + (size_t)bblk * (NB_F0 * 16);
    for (int c = tid; c < (8 * NB_F0 * 16) / 8; c += 256)
      *(s16x8*)&x0s[c * 8] = *(const s16x8*)&src[c * 8];
  }
  __syncthreads();  // only barrier in the kernel

  // ---- Xi A-fragments: A[m=d=col][k=q*8+i], resident in regs ----
  s16x8 af[2][2];
  auto load_af = [&](int pass) {
#pragma unroll
    for (int bi = 0; bi < 2; ++bi)
#pragma unroll
      for (int kc = 0; kc < 2; ++kc)
        af[bi][kc] = *(const s16x8*)(XiT +
            ((size_t)(bwave + bi) * 16 + col) * FI_PAD + pass * 64 + kc * 32 + q * 8);
  };
  load_af(0);

  // ---- W B-fragment stream: B[k=q*8+i][n=h=col] ----
  const unsigned short* wbase = Wf + ((size_t)ht * KCT) * 512 + lane * 8;
  auto wload = [&](int s, s16x8* dst) {
    const int pass = (KPASS == 2 && s >= NB_F0) ? 1 : 0;
    const int j = s - pass * NB_F0;
    const unsigned short* p = wbase + ((size_t)j * 8 * KCT + pass * 2) * 512;
    dst[0] = *(const s16x8*)p;
    dst[1] = *(const s16x8*)(p + 512);
  };

  f32x4 Xacc[2];
  Xacc[0] = f32x4{0.f, 0.f, 0.f, 0.f};
  Xacc[1] = f32x4{0.f, 0.f, 0.f, 0.f};

  auto stage = [&](int s, const s16x8* wfr) {
    const int j = (KPASS == 2 && s >= NB_F0) ? s - NB_F0 : s;
    f32x4 y[2];
    y[0] = f32x4{0.f, 0.f, 0.f, 0.f};
    y[1] = f32x4{0.f, 0.f, 0.f, 0.f};
#pragma unroll
    for (int kc = 0; kc < 2; ++kc)
#pragma unroll
      for (int bi = 0; bi < 2; ++bi)
        y[bi] = __builtin_amdgcn_mfma_f32_16x16x32_bf16(af[bi][kc], wfr[kc],
                                                        y[bi], 0, 0, 0);
#pragma unroll
    for (int bi = 0; bi < 2; ++bi) {
      const ushort4 u =
          *(const ushort4*)&x0s[(((wv * 2 + bi) * NB_F0) + j) * 16 + q * 4];
      Xacc[bi][0] += bf16_to_f32(u.x) * y[bi][0];
      Xacc[bi][1] += bf16_to_f32(u.y) * y[bi][1];
      Xacc[bi][2] += bf16_to_f32(u.z) * y[bi][2];
      Xacc[bi][3] += bf16_to_f32(u.w) * y[bi][3];
    }
  };

  // ---- 4-deep prefetch ring (distance 3), manual unroll-by-4 ----
  s16x8 wf0[2], wf1[2], wf2[2], wf3[2];
  wload(0, wf0);
  wload(1, wf1);
  wload(2, wf2);
  int s = 0;
  for (; s + 3 < S; s += 4) {
    wload(s + 3, wf3);
    stage(s, wf0);
    if (s + 4 < S) { wload(s + 4, wf0); }
    stage(s + 1, wf1);
    if (s + 5 < S) { wload(s + 5, wf1); }
    stage(s + 2, wf2);
    if (s + 6 < S) { wload(s + 6, wf2); }
    if (KPASS == 2 && s + 3 == NB_F0) load_af(1);  // af K-window switch (39%4==3)
    stage(s + 3, wf3);
  }
  // constexpr tail (S=39 -> 3, S=78 -> 2); buffers follow the mod-4 rotation
  constexpr int TAIL = S & 3;
  if (TAIL >= 1) stage(S - TAIL + 0, wf0);
  if (TAIL >= 2) stage(S - TAIL + 1, wf1);
  if (TAIL >= 3) stage(S - TAIL + 2, wf2);

  // ---- epilogue: bias, optional Xn store, d-reduction (in-lane r + q-shuffles) ----
  const float bias_v = bias[ht * 16 + col];
#pragma unroll
  for (int bi = 0; bi < 2; ++bi) {
    const int b = bwave + bi;
    float v[4];
#pragma unroll
    for (int r = 0; r < 4; ++r) v[r] = Xacc[bi][r] + bias_v;
    if (STORE_XN) {
#pragma unroll
      for (int r = 0; r < 4; ++r)
        XnT[((size_t)b * 16 + q * 4 + r) * NB_H + ht * 16 + col] = rne_bf16(v[r]);
    }
    float tot = (v[0] + v[1]) + (v[2] + v[3]);
    tot += __shfl_xor(tot, 16);
    tot += __shfl_xor(tot, 32);
    if (q == 0) outp[(size_t)b * 384 + ht * 16 + col] = tot;
  }
}

extern "C" void kernel_launch(void* const* d_in, const int* in_sizes, int n_in,
                              void* d_out, int out_size, void* d_ws, size_t ws_size,
                              hipStream_t stream) {
  (void)in_sizes; (void)n_in; (void)out_size; (void)ws_size;
  const float* X0g = (const float*)d_in[0];
  const float* W0  = (const float*)d_in[1];
  const float* b0  = (const float*)d_in[2];
  const float* W1  = (const float*)d_in[3];
  const float* b1  = (const float*)d_in[4];
  const float* W2  = (const float*)d_in[5];
  const float* b2  = (const float*)d_in[6];
  float* out = (float*)d_out;

  char* p = (char*)d_ws;
  unsigned short* X0T = (unsigned short*)p; p += (size_t)NB_B * 16 * 64 * 2;
  unsigned short* X0c = (unsigned short*)p; p += (size_t)NB_B * NB_F0 * 16 * 2;
  unsigned short* X1T = (unsigned short*)p; p += (size_t)NB_B * 16 * 128 * 2;
  unsigned short* X2T = (unsigned short*)p; p += (size_t)NB_B * 16 * 128 * 2;
  unsigned short* Wf0 = (unsigned short*)p; p += (size_t)NB_F0 * 8 * 2 * 512 * 2;
  unsigned short* Wf1 = (unsigned short*)p; p += (size_t)NB_F0 * 8 * 4 * 512 * 2;
  unsigned short* Wf2 = (unsigned short*)p; p += (size_t)NB_F0 * 8 * 4 * 512 * 2;

  hipLaunchKernelGGL(prep_x0_kernel, dim3(NB_B), dim3(256), 0, stream,
                     X0g, X0T, X0c);
  const int tw0  = NB_F0 * 8 * 2 * 512;   // KCT=2
  const int tw12 = NB_F0 * 8 * 4 * 512;   // KCT=4
  hipLaunchKernelGGL(prep_w_kernel, dim3((tw0 + 255) / 256), dim3(256), 0, stream,
                     W0, Wf0, 39, 1, tw0);
  hipLaunchKernelGGL(prep_w_kernel, dim3((tw12 + 255) / 256), dim3(256), 0, stream,
                     W1, Wf1, 128, 2, tw12);
  hipLaunchKernelGGL(prep_w_kernel, dim3((tw12 + 255) / 256), dim3(256), 0, stream,
                     W2, Wf2, 128, 2, tw12);

  hipLaunchKernelGGL((cin_layer<64, true>),   dim3(4096), dim3(256), 0, stream,
                     Wf0, X0T, X0c, b0, X1T, out + 0);
  hipLaunchKernelGGL((cin_layer<128, true>),  dim3(4096), dim3(256), 0, stream,
                     Wf1, X1T, X0c, b1, X2T, out + 128);
  hipLaunchKernelGGL((cin_layer<128, false>), dim3(4096), dim3(256), 0, stream,
                     Wf2, X2T, X0c, b2, (unsigned short*)nullptr, out + 256);
}

// Round 8
// 338.387 us; speedup vs baseline: 4.5905x; 1.0350x over previous
//
#include <hip/hip_runtime.h>
#include <stdint.h>

// CIN layers: Xn[b,h,d] = sum_{j,k} W[h,j,k] * X0[b,j,d] * Xi[b,k,d] + bias[h]
// Factored:   y[d,h]    = sum_k Xi[b,k,d] * W[h,j,k]   then Xacc += x0[b,j,d]*y.
// R8: switch to mfma_f32_32x32x16_bf16 with A rows m = b'*16 + d (2 b's x 16 d)
// and B cols = 32 h. One stage (j, 64-wide K window) = 4 chained MFMAs covering
// 2b x 32h -- 4x the output of the R7 16x16x32 stage for ~1/4 the VALU overhead
// per output (R7 was VALU-overhead-bound: ~110 VALU cyc/stage at 51% VALUBusy).
// x0 staged in LDS as f32 (no converts; half-wave-broadcast ds_read_b128).
// W streamed from global in fragment-linear units, double-buffered in regs.
// Grid: 2048 blocks = 512 b-groups (low bits -> XCD-resident XiT slice) x 4
// h-tiles; block = 4 waves x 2 b x 32 h.

#define NB_F0 39
#define NB_H  128
#define NB_B  4096

typedef float f32x4  __attribute__((ext_vector_type(4)));
typedef float f32x16 __attribute__((ext_vector_type(16)));
typedef short s16x8  __attribute__((ext_vector_type(8)));

__device__ __forceinline__ unsigned short rne_bf16(float f) {
  union { float f; unsigned u; } v; v.f = f;
  return (unsigned short)((v.u + 0x7fffu + ((v.u >> 16) & 1u)) >> 16);
}
__device__ __forceinline__ float bf16_to_f32(unsigned short s) {
  union { unsigned u; float f; } v; v.u = ((unsigned)s) << 16;
  return v.f;
}

// X0 f32 [B][39][16] -> X0T bf16 [B][16][64] (k=j zero-padded, layer-0 A source)
//                    -> X0f f32  [B][39][16] (bf16-rounded, widened; x0 factors)
__global__ void prep_x0_kernel(const float* __restrict__ X0g,
                               unsigned short* __restrict__ X0T,
                               float* __restrict__ X0f) {
  const int b = blockIdx.x;
  const int t = threadIdx.x;
  {
    const int d  = t >> 4;
    const int k4 = (t & 15) << 2;
    unsigned short vv[4];
#pragma unroll
    for (int i = 0; i < 4; ++i) {
      const int k = k4 + i;
      vv[i] = (k < NB_F0) ? rne_bf16(X0g[(size_t)b * (NB_F0 * 16) + k * 16 + d])
                          : (unsigned short)0;
    }
    ushort4 pk; pk.x = vv[0]; pk.y = vv[1]; pk.z = vv[2]; pk.w = vv[3];
    *(ushort4*)&X0T[((size_t)b * 16 + d) * 64 + k4] = pk;
  }
  for (int idx = t; idx < NB_F0 * 16; idx += 256)
    X0f[(size_t)b * (NB_F0 * 16) + idx] =
        bf16_to_f32(rne_bf16(X0g[(size_t)b * (NB_F0 * 16) + idx]));
}

// W f32 [128][39*Fi] -> Wf bf16 fragment-linear for 32x32x16 B-operand:
//   Wf[(((j*4 + t)*KC16 + c)*64 + lane)*8 + i]
//     = W[h = t*32 + (lane&31)][j, k = c*16 + (lane>>5)*8 + i]   (0 if k>=Fi)
// One (j,t,c) unit = 1024 B = one wave dwordx4 load.
__global__ void prep_w_kernel(const float* __restrict__ Wsrc,
                              unsigned short* __restrict__ Wdst,
                              int Fi, int kshift, int total) {
  int idx = blockIdx.x * 256 + threadIdx.x;
  if (idx >= total) return;
  const int i    = idx & 7;
  const int lane = (idx >> 3) & 63;
  const int c    = (idx >> 9) & ((1 << kshift) - 1);
  const int jt   = idx >> (9 + kshift);
  const int t    = jt & 3;
  const int j    = jt >> 2;
  const int h = t * 32 + (lane & 31);
  const int k = c * 16 + ((lane >> 5) << 3) + i;
  unsigned short v = 0;
  if (k < Fi) v = rne_bf16(Wsrc[(size_t)h * (NB_F0 * Fi) + j * Fi + k]);
  Wdst[idx] = v;
}

template <int FI_PAD, bool STORE_XN>
__global__ __launch_bounds__(256, 3) void cin_layer(
    const unsigned short* __restrict__ Wf,   // fragment-linear W (see prep)
    const unsigned short* __restrict__ XiT,  // [B][16][FI_PAD] bf16
    const float* __restrict__ X0f,           // [B][39][16] f32 (bf16-rounded)
    const float* __restrict__ bias,          // [128]
    unsigned short* __restrict__ XnT,        // [B][16][128] bf16 (or unused)
    float* __restrict__ outp)                // d_out + layer*128, stride 384
{
  constexpr int KPASS = FI_PAD / 64;   // 1 or 2 K-passes of 64
  constexpr int KC16  = FI_PAD / 16;   // 16-wide k-chunks total
  constexpr int S     = NB_F0 * KPASS;

  __shared__ __attribute__((aligned(16))) float x0s[8 * NB_F0 * 16];  // 19968 B

  const int tid  = threadIdx.x;
  const int lane = tid & 63;
  const int wv   = tid >> 6;
  const int L    = lane >> 5;       // k-half selector
  const int col  = lane & 31;       // A row m / B col h(within tile)
  // XCD swizzle: low 9 bits = b-group (blockIdx%8 == XCD id), high 2 = h-tile.
  const int ht   = blockIdx.x >> 9;              // 0..3 (32 h each)
  const int bblk = (blockIdx.x & 511) * 8;
  const int bwave = bblk + wv * 2;

  // ---- stage x0 factors as f32 (flat copy, coalesced; 4992 floats) ----
  {
    const f32x4* src = (const f32x4*)(X0f + (size_t)bblk * (NB_F0 * 16));
    f32x4* dst = (f32x4*)x0s;
    for (int c = tid; c < (8 * NB_F0 * 16) / 4; c += 256) dst[c] = src[c];
  }
  __syncthreads();  // only barrier in the kernel

  // ---- Xi A-fragments: A[m = b'*16+d = col][k = c*16 + L*8 + i] ----
  s16x8 af[4];
  auto load_af = [&](int pass) {
    const unsigned short* base = XiT +
        ((size_t)(bwave + (col >> 4)) * 16 + (col & 15)) * FI_PAD + pass * 64 + L * 8;
#pragma unroll
    for (int c = 0; c < 4; ++c) af[c] = *(const s16x8*)(base + c * 16);
  };
  load_af(0);

  // ---- W B-fragment stream: B[k][n=h], 4 chunks (=one 64-wide window)/stage ----
  const unsigned short* wbase = Wf + ((size_t)ht * KC16) * 512 + lane * 8;
  auto wload = [&](int s, s16x8* dst) {
    const int pass = (KPASS == 2 && s >= NB_F0) ? 1 : 0;
    const int j = s - pass * NB_F0;
    const unsigned short* p = wbase + ((size_t)j * 4 * KC16 + pass * 4) * 512;
#pragma unroll
    for (int c = 0; c < 4; ++c) dst[c] = *(const s16x8*)(p + c * 512);
  };

  f32x16 Xacc, kZero;
#pragma unroll
  for (int r = 0; r < 16; ++r) { Xacc[r] = 0.f; kZero[r] = 0.f; }

  auto stage = [&](int s, const s16x8* wfr) {
    const int j = (KPASS == 2 && s >= NB_F0) ? s - NB_F0 : s;
    f32x16 y;
    y = __builtin_amdgcn_mfma_f32_32x32x16_bf16(af[0], wfr[0], kZero, 0, 0, 0);
    y = __builtin_amdgcn_mfma_f32_32x32x16_bf16(af[1], wfr[1], y, 0, 0, 0);
    y = __builtin_amdgcn_mfma_f32_32x32x16_bf16(af[2], wfr[2], y, 0, 0, 0);
    y = __builtin_amdgcn_mfma_f32_32x32x16_bf16(af[3], wfr[3], y, 0, 0, 0);
    // x0 scale: reg r -> b' = r>>3, d = (r&3) + 8*((r>>2)&1) + 4*L
    const float* xb = &x0s[((wv * 2) * NB_F0 + j) * 16 + 4 * L];
    const f32x4 x00 = *(const f32x4*)(xb);                    // b'=0, d=4L+0..3
    const f32x4 x01 = *(const f32x4*)(xb + 8);                // b'=0, d=8+4L+..
    const f32x4 x10 = *(const f32x4*)(xb + NB_F0 * 16);       // b'=1
    const f32x4 x11 = *(const f32x4*)(xb + NB_F0 * 16 + 8);   // b'=1
#pragma unroll
    for (int r = 0; r < 4; ++r) {
      Xacc[r]      += x00[r] * y[r];
      Xacc[r + 4]  += x01[r] * y[r + 4];
      Xacc[r + 8]  += x10[r] * y[r + 8];
      Xacc[r + 12] += x11[r] * y[r + 12];
    }
  };

  // ---- double-buffered W stream (R6-proven shape) ----
  s16x8 wfA[4], wfB[4];
  wload(0, wfA);
  for (int s = 0; s + 1 < S; s += 2) {
    wload(s + 1, wfB);
    stage(s, wfA);
    if (s + 2 < S) wload(s + 2, wfA);
    if (KPASS == 2 && s + 1 == NB_F0) load_af(1);  // af K-window switch
    stage(s + 1, wfB);
  }
  if (S & 1) stage(S - 1, wfA);

  // ---- epilogue ----
  const float bias_v = bias[ht * 32 + col];
  if (STORE_XN) {
#pragma unroll
    for (int r = 0; r < 16; ++r) {
      const int bp = r >> 3;
      const int d  = (r & 3) + 8 * ((r >> 2) & 1) + 4 * L;
      XnT[((size_t)(bwave + bp) * 16 + d) * NB_H + ht * 32 + col] =
          rne_bf16(Xacc[r] + bias_v);
    }
  }
  float s0 = 8.f * bias_v, s1 = 8.f * bias_v;
#pragma unroll
  for (int r = 0; r < 8; ++r) { s0 += Xacc[r]; s1 += Xacc[r + 8]; }
  s0 += __shfl_xor(s0, 32);   // combine the two d-halves (L=0/1)
  s1 += __shfl_xor(s1, 32);
  if (lane < 32) {
    outp[(size_t)bwave * 384 + ht * 32 + lane] = s0;
    outp[(size_t)(bwave + 1) * 384 + ht * 32 + lane] = s1;
  }
}

extern "C" void kernel_launch(void* const* d_in, const int* in_sizes, int n_in,
                              void* d_out, int out_size, void* d_ws, size_t ws_size,
                              hipStream_t stream) {
  (void)in_sizes; (void)n_in; (void)out_size; (void)ws_size;
  const float* X0g = (const float*)d_in[0];
  const float* W0  = (const float*)d_in[1];
  const float* b0  = (const float*)d_in[2];
  const float* W1  = (const float*)d_in[3];
  const float* b1  = (const float*)d_in[4];
  const float* W2  = (const float*)d_in[5];
  const float* b2  = (const float*)d_in[6];
  float* out = (float*)d_out;

  char* p = (char*)d_ws;
  unsigned short* X0T = (unsigned short*)p; p += (size_t)NB_B * 16 * 64 * 2;
  float*          X0f = (float*)p;          p += (size_t)NB_B * NB_F0 * 16 * 4;
  unsigned short* X1T = (unsigned short*)p; p += (size_t)NB_B * 16 * 128 * 2;
  unsigned short* X2T = (unsigned short*)p; p += (size_t)NB_B * 16 * 128 * 2;
  unsigned short* Wf0 = (unsigned short*)p; p += (size_t)NB_F0 * 4 * 4 * 512 * 2;
  unsigned short* Wf1 = (unsigned short*)p; p += (size_t)NB_F0 * 4 * 8 * 512 * 2;
  unsigned short* Wf2 = (unsigned short*)p; p += (size_t)NB_F0 * 4 * 8 * 512 * 2;

  hipLaunchKernelGGL(prep_x0_kernel, dim3(NB_B), dim3(256), 0, stream,
                     X0g, X0T, X0f);
  const int tw0  = NB_F0 * 4 * 4 * 512;   // KC16=4
  const int tw12 = NB_F0 * 4 * 8 * 512;   // KC16=8
  hipLaunchKernelGGL(prep_w_kernel, dim3((tw0 + 255) / 256), dim3(256), 0, stream,
                     W0, Wf0, 39, 2, tw0);
  hipLaunchKernelGGL(prep_w_kernel, dim3((tw12 + 255) / 256), dim3(256), 0, stream,
                     W1, Wf1, 128, 3, tw12);
  hipLaunchKernelGGL(prep_w_kernel, dim3((tw12 + 255) / 256), dim3(256), 0, stream,
                     W2, Wf2, 128, 3, tw12);

  hipLaunchKernelGGL((cin_layer<64, true>),   dim3(2048), dim3(256), 0, stream,
                     Wf0, X0T, X0f, b0, X1T, out + 0);
  hipLaunchKernelGGL((cin_layer<128, true>),  dim3(2048), dim3(256), 0, stream,
                     Wf1, X1T, X0f, b1, X2T, out + 128);
  hipLaunchKernelGGL((cin_layer<128, false>), dim3(2048), dim3(256), 0, stream,
                     Wf2, X2T, X0f, b2, (unsigned short*)nullptr, out + 256);
}

// Round 9
// 328.308 us; speedup vs baseline: 4.7314x; 1.0307x over previous
//
#include <hip/hip_runtime.h>
#include <stdint.h>

// CIN layers: Xn[b,h,d] = sum_{j,k} W[h,j,k] * X0[b,j,d] * Xi[b,k,d] + bias[h]
// y[d,h] = sum_k Xi*W (mfma_32x32x16, A rows m=b'*16+d, B cols=32h), then
// Xacc += x0[b,j,d]*y.
// R8 was L1-BW bound: every wave streamed the full W tile through its own
// registers (2.56 GB of L1 service per big layer ~= 65 us -> ~112 us pinned).
// R9: (1) W staged once per block via global_load_lds (proper addrspacecast,
// NOT the R2 int-truncation), double-buffered 4KB LDS, 1 barrier/stage;
// (2) nb=4 b/wave (two MFMA chains share the W fragments) -> halves
// wave-streams. Per-block-stage L1 service 16KB -> 4KB.
// Grid: 1024 blocks = 256 b-groups (low bits -> XCD-local XiT) x 4 h-tiles;
// block = 4 waves x 4 b x 32 h. x0 staged bf16 d-permuted: 1 ds_read_b128
// per b-pair per stage.

#define NB_F0 39
#define NB_H  128
#define NB_B  4096

typedef float f32x4  __attribute__((ext_vector_type(4)));
typedef float f32x16 __attribute__((ext_vector_type(16)));
typedef short s16x8  __attribute__((ext_vector_type(8)));

__device__ __forceinline__ void dma16(const void* g, void* l) {
  __builtin_amdgcn_global_load_lds(
      (const __attribute__((address_space(1))) unsigned int*)g,
      (__attribute__((address_space(3))) unsigned int*)l, 16, 0, 0);
}

__device__ __forceinline__ unsigned short rne_bf16(float f) {
  union { float f; unsigned u; } v; v.f = f;
  return (unsigned short)((v.u + 0x7fffu + ((v.u >> 16) & 1u)) >> 16);
}
__device__ __forceinline__ float bf16_to_f32(unsigned short s) {
  union { unsigned u; float f; } v; v.u = ((unsigned)s) << 16;
  return v.f;
}

// X0 f32 [B][39][16] -> X0T bf16 [B][16][64] (k=j zero-padded, layer-0 A source)
//                    -> X0c bf16 [B][39][16] with d-PERMUTED inner dim:
//   pos <-> d swap bits 2 and 3 (self-inverse), so a lane's 8 x0 factors for
//   MFMA regs r=0..7 (d = (r&3)+8*((r>>2)&1)+4L) are one contiguous 16B run.
__global__ void prep_x0_kernel(const float* __restrict__ X0g,
                               unsigned short* __restrict__ X0T,
                               unsigned short* __restrict__ X0c) {
  const int b = blockIdx.x;
  const int t = threadIdx.x;
  {
    const int d  = t >> 4;
    const int k4 = (t & 15) << 2;
    unsigned short vv[4];
#pragma unroll
    for (int i = 0; i < 4; ++i) {
      const int k = k4 + i;
      vv[i] = (k < NB_F0) ? rne_bf16(X0g[(size_t)b * (NB_F0 * 16) + k * 16 + d])
                          : (unsigned short)0;
    }
    ushort4 pk; pk.x = vv[0]; pk.y = vv[1]; pk.z = vv[2]; pk.w = vv[3];
    *(ushort4*)&X0T[((size_t)b * 16 + d) * 64 + k4] = pk;
  }
  for (int idx = t; idx < NB_F0 * 16; idx += 256) {
    const int j = idx >> 4, pos = idx & 15;
    const int d = (pos & 3) | (((pos >> 3) & 1) << 2) | (((pos >> 2) & 1) << 3);
    X0c[(size_t)b * (NB_F0 * 16) + idx] =
        rne_bf16(X0g[(size_t)b * (NB_F0 * 16) + j * 16 + d]);
  }
}

// W f32 [128][39*Fi] -> Wf bf16 fragment-linear for 32x32x16 B-operand:
//   Wf[(((j*4 + t)*KC16 + c)*64 + lane)*8 + i]
//     = W[h = t*32 + (lane&31)][j, k = c*16 + (lane>>5)*8 + i]   (0 if k>=Fi)
__global__ void prep_w_kernel(const float* __restrict__ Wsrc,
                              unsigned short* __restrict__ Wdst,
                              int Fi, int kshift, int total) {
  int idx = blockIdx.x * 256 + threadIdx.x;
  if (idx >= total) return;
  const int i    = idx & 7;
  const int lane = (idx >> 3) & 63;
  const int c    = (idx >> 9) & ((1 << kshift) - 1);
  const int jt   = idx >> (9 + kshift);
  const int t    = jt & 3;
  const int j    = jt >> 2;
  const int h = t * 32 + (lane & 31);
  const int k = c * 16 + ((lane >> 5) << 3) + i;
  unsigned short v = 0;
  if (k < Fi) v = rne_bf16(Wsrc[(size_t)h * (NB_F0 * Fi) + j * Fi + k]);
  Wdst[idx] = v;
}

template <int FI_PAD, bool STORE_XN>
__global__ __launch_bounds__(256, 3) void cin_layer(
    const unsigned short* __restrict__ Wf,   // fragment-linear W (see prep)
    const unsigned short* __restrict__ XiT,  // [B][16][FI_PAD] bf16
    const unsigned short* __restrict__ X0c,  // [B][39][16] bf16, d-permuted
    const float* __restrict__ bias,          // [128]
    unsigned short* __restrict__ XnT,        // [B][16][128] bf16 (or unused)
    float* __restrict__ outp)                // d_out + layer*128, stride 384
{
  constexpr int KPASS = FI_PAD / 64;   // 1 or 2 K-passes of 64
  constexpr int KC16  = FI_PAD / 16;   // 16-wide k-chunks total
  constexpr int S     = NB_F0 * KPASS;

  __shared__ __attribute__((aligned(16))) unsigned short Wlds[2][2048]; // 2x4KB
  __shared__ __attribute__((aligned(16))) unsigned short x0s[16 * NB_F0 * 16];

  const int tid  = threadIdx.x;
  const int lane = tid & 63;
  const int wv   = tid >> 6;
  const int L    = lane >> 5;       // k-half selector
  const int col  = lane & 31;       // A row m / B col
  const int ht   = blockIdx.x >> 8;            // 0..3 (32 h each)
  const int bblk = (blockIdx.x & 255) * 16;    // 16 b per block
  const int bwave = bblk + wv * 4;             // 4 b per wave

  // ---- W DMA: wave wv stages chunk wv (1 KB) of the 4 KB stage tile ----
  auto dma_stage = [&](int s, int buf) {
    const int pass = (KPASS == 2 && s >= NB_F0) ? 1 : 0;
    const int j = s - pass * NB_F0;
    const unsigned short* src =
        Wf + (((size_t)(j * 4 + ht) * KC16) + pass * 4 + wv) * 512 + lane * 8;
    dma16(src, &Wlds[buf][wv * 512]);   // lane i lands at +i*16B: fragment order
  };

  // ---- stage x0 factors (bf16, flat coalesced copy: 9984 shorts) ----
  {
    const unsigned short* src = X0c + (size_t)bblk * (NB_F0 * 16);
    for (int c = tid; c < (16 * NB_F0 * 16) / 8; c += 256)
      *(s16x8*)&x0s[c * 8] = *(const s16x8*)&src[c * 8];
  }
  dma_stage(0, 0);

  // ---- Xi A-fragments: pair P covers b' = 2P + (col>>4); resident in regs ----
  s16x8 af[2][4];
  auto load_af = [&](int pass) {
#pragma unroll
    for (int P = 0; P < 2; ++P) {
      const unsigned short* base = XiT +
          ((size_t)(bwave + 2 * P + (col >> 4)) * 16 + (col & 15)) * FI_PAD +
          pass * 64 + L * 8;
#pragma unroll
      for (int c = 0; c < 4; ++c) af[P][c] = *(const s16x8*)(base + c * 16);
    }
  };
  load_af(0);

  f32x16 Xacc[2], kZero;
#pragma unroll
  for (int r = 0; r < 16; ++r) { Xacc[0][r] = 0.f; Xacc[1][r] = 0.f; kZero[r] = 0.f; }

  const int x0base = (wv * 4) * (NB_F0 * 16) + L * 8;

  for (int s = 0; s < S; ++s) {
    __syncthreads();                    // publishes Wlds[s&1]; x0s on s==0
    if (s + 1 < S) dma_stage(s + 1, (s + 1) & 1);
    if (KPASS == 2 && s == NB_F0) load_af(1);   // af K-window switch

    const int j = (KPASS == 2 && s >= NB_F0) ? s - NB_F0 : s;
    const unsigned short* wb = &Wlds[s & 1][lane * 8];
    const s16x8 w0 = *(const s16x8*)(wb);
    const s16x8 w1 = *(const s16x8*)(wb + 512);
    const s16x8 w2 = *(const s16x8*)(wb + 1024);
    const s16x8 w3 = *(const s16x8*)(wb + 1536);

    f32x16 y0, y1;
    y0 = __builtin_amdgcn_mfma_f32_32x32x16_bf16(af[0][0], w0, kZero, 0, 0, 0);
    y1 = __builtin_amdgcn_mfma_f32_32x32x16_bf16(af[1][0], w0, kZero, 0, 0, 0);
    y0 = __builtin_amdgcn_mfma_f32_32x32x16_bf16(af[0][1], w1, y0, 0, 0, 0);
    y1 = __builtin_amdgcn_mfma_f32_32x32x16_bf16(af[1][1], w1, y1, 0, 0, 0);
    y0 = __builtin_amdgcn_mfma_f32_32x32x16_bf16(af[0][2], w2, y0, 0, 0, 0);
    y1 = __builtin_amdgcn_mfma_f32_32x32x16_bf16(af[1][2], w2, y1, 0, 0, 0);
    y0 = __builtin_amdgcn_mfma_f32_32x32x16_bf16(af[0][3], w3, y0, 0, 0, 0);
    y1 = __builtin_amdgcn_mfma_f32_32x32x16_bf16(af[1][3], w3, y1, 0, 0, 0);

    // x0 scale: chain P reg r -> b' = 2P + (r>>3); local m = r&7 matches the
    // d-permuted 8-value run at x0s[(b'*39 + j)*16 + L*8].
#pragma unroll
    for (int P = 0; P < 2; ++P) {
      const f32x16& y = (P == 0) ? y0 : y1;
#pragma unroll
      for (int bh = 0; bh < 2; ++bh) {
        const s16x8 xu = *(const s16x8*)
            &x0s[x0base + (2 * P + bh) * (NB_F0 * 16) + j * 16];
#pragma unroll
        for (int m = 0; m < 8; ++m)
          Xacc[P][bh * 8 + m] +=
              bf16_to_f32((unsigned short)xu[m]) * y[bh * 8 + m];
      }
    }
  }

  // ---- epilogue ----
  const float bias_v = bias[ht * 32 + col];
#pragma unroll
  for (int P = 0; P < 2; ++P) {
#pragma unroll
    for (int bh = 0; bh < 2; ++bh) {
      const int b = bwave + 2 * P + bh;
      float v[8];
#pragma unroll
      for (int m = 0; m < 8; ++m) v[m] = Xacc[P][bh * 8 + m] + bias_v;
      if (STORE_XN) {
#pragma unroll
        for (int m = 0; m < 8; ++m) {
          const int d = (m & 3) + 8 * ((m >> 2) & 1) + 4 * L;
          XnT[((size_t)b * 16 + d) * NB_H + ht * 32 + col] = rne_bf16(v[m]);
        }
      }
      float tot = ((v[0] + v[1]) + (v[2] + v[3])) + ((v[4] + v[5]) + (v[6] + v[7]));
      tot += __shfl_xor(tot, 32);
      if (lane < 32) outp[(size_t)b * 384 + ht * 32 + lane] = tot;
    }
  }
}

extern "C" void kernel_launch(void* const* d_in, const int* in_sizes, int n_in,
                              void* d_out, int out_size, void* d_ws, size_t ws_size,
                              hipStream_t stream) {
  (void)in_sizes; (void)n_in; (void)out_size; (void)ws_size;
  const float* X0g = (const float*)d_in[0];
  const float* W0  = (const float*)d_in[1];
  const float* b0  = (const float*)d_in[2];
  const float* W1  = (const float*)d_in[3];
  const float* b1  = (const float*)d_in[4];
  const float* W2  = (const float*)d_in[5];
  const float* b2  = (const float*)d_in[6];
  float* out = (float*)d_out;

  char* p = (char*)d_ws;
  unsigned short* X0T = (unsigned short*)p; p += (size_t)NB_B * 16 * 64 * 2;
  unsigned short* X0c = (unsigned short*)p; p += (size_t)NB_B * NB_F0 * 16 * 2;
  unsigned short* X1T = (unsigned short*)p; p += (size_t)NB_B * 16 * 128 * 2;
  unsigned short* X2T = (unsigned short*)p; p += (size_t)NB_B * 16 * 128 * 2;
  unsigned short* Wf0 = (unsigned short*)p; p += (size_t)NB_F0 * 4 * 4 * 512 * 2;
  unsigned short* Wf1 = (unsigned short*)p; p += (size_t)NB_F0 * 4 * 8 * 512 * 2;
  unsigned short* Wf2 = (unsigned short*)p; p += (size_t)NB_F0 * 4 * 8 * 512 * 2;

  hipLaunchKernelGGL(prep_x0_kernel, dim3(NB_B), dim3(256), 0, stream,
                     X0g, X0T, X0c);
  const int tw0  = NB_F0 * 4 * 4 * 512;   // KC16=4
  const int tw12 = NB_F0 * 4 * 8 * 512;   // KC16=8
  hipLaunchKernelGGL(prep_w_kernel, dim3((tw0 + 255) / 256), dim3(256), 0, stream,
                     W0, Wf0, 39, 2, tw0);
  hipLaunchKernelGGL(prep_w_kernel, dim3((tw12 + 255) / 256), dim3(256), 0, stream,
                     W1, Wf1, 128, 3, tw12);
  hipLaunchKernelGGL(prep_w_kernel, dim3((tw12 + 255) / 256), dim3(256), 0, stream,
                     W2, Wf2, 128, 3, tw12);

  hipLaunchKernelGGL((cin_layer<64, true>),   dim3(1024), dim3(256), 0, stream,
                     Wf0, X0T, X0c, b0, X1T, out + 0);
  hipLaunchKernelGGL((cin_layer<128, true>),  dim3(1024), dim3(256), 0, stream,
                     Wf1, X1T, X0c, b1, X2T, out + 128);
  hipLaunchKernelGGL((cin_layer<128, false>), dim3(1024), dim3(256), 0, stream,
                     Wf2, X2T, X0c, b2, (unsigned short*)nullptr, out + 256);
}

// Round 10
// 316.332 us; speedup vs baseline: 4.9105x; 1.0379x over previous
//
#include <hip/hip_runtime.h>
#include <stdint.h>

// CIN layers: Xn[b,h,d] = sum_{j,k} W[h,j,k] * X0[b,j,d] * Xi[b,k,d] + bias[h]
// y[d,h] = sum_k Xi*W (mfma_32x32x16, A rows m=b'*16+d, B cols=32h), then
// Xacc += x0[b,j,d]*y.
// R9 audit: pinned ~108us/layer = LDS (~39us: 4x W-read amplification) +
// VALU (~36us: 64 cvt + 32 fmac + addr per wave-stage) with MFMA only ~8us.
// R10: nb=8 (4 chains share each W fragment -> W-LDS and overhead per output
// halved); x0 bf16 runs unpacked to float2 + elementwise_fma so backend can
// emit v_pk_fma_f32. launch_bounds(256,2): ~195 unified regs, no spill risk
// (R4/R5 lesson); LDS 48KB/block still allows 3 blk/CU if regs land <=170.
// Grid: 512 blocks = 128 b-groups (XCD-local XiT slice) x 4 h-tiles;
// block = 4 waves x 8 b x 32 h. W staged 4KB/stage via global_load_lds,
// double-buffered, 1 barrier/stage.

#define NB_F0 39
#define NB_H  128
#define NB_B  4096

typedef float f32x4  __attribute__((ext_vector_type(4)));
typedef float f32x16 __attribute__((ext_vector_type(16)));
typedef short s16x8  __attribute__((ext_vector_type(8)));

__device__ __forceinline__ void dma16(const void* g, void* l) {
  __builtin_amdgcn_global_load_lds(
      (const __attribute__((address_space(1))) unsigned int*)g,
      (__attribute__((address_space(3))) unsigned int*)l, 16, 0, 0);
}

__device__ __forceinline__ unsigned short rne_bf16(float f) {
  union { float f; unsigned u; } v; v.f = f;
  return (unsigned short)((v.u + 0x7fffu + ((v.u >> 16) & 1u)) >> 16);
}
__device__ __forceinline__ float bf16_to_f32(unsigned short s) {
  union { unsigned u; float f; } v; v.u = ((unsigned)s) << 16;
  return v.f;
}

// X0 f32 [B][39][16] -> X0T bf16 [B][16][64] (k=j zero-padded, layer-0 A source)
//                    -> X0c bf16 [B][39][16] with d-PERMUTED inner dim
//   (pos<->d swap bits 2,3) so a lane's 8 x0 factors for MFMA regs r=0..7
//   (d = (r&3)+8*((r>>2)&1)+4L) are one contiguous 16B run.
__global__ void prep_x0_kernel(const float* __restrict__ X0g,
                               unsigned short* __restrict__ X0T,
                               unsigned short* __restrict__ X0c) {
  const int b = blockIdx.x;
  const int t = threadIdx.x;
  {
    const int d  = t >> 4;
    const int k4 = (t & 15) << 2;
    unsigned short vv[4];
#pragma unroll
    for (int i = 0; i < 4; ++i) {
      const int k = k4 + i;
      vv[i] = (k < NB_F0) ? rne_bf16(X0g[(size_t)b * (NB_F0 * 16) + k * 16 + d])
                          : (unsigned short)0;
    }
    ushort4 pk; pk.x = vv[0]; pk.y = vv[1]; pk.z = vv[2]; pk.w = vv[3];
    *(ushort4*)&X0T[((size_t)b * 16 + d) * 64 + k4] = pk;
  }
  for (int idx = t; idx < NB_F0 * 16; idx += 256) {
    const int j = idx >> 4, pos = idx & 15;
    const int d = (pos & 3) | (((pos >> 3) & 1) << 2) | (((pos >> 2) & 1) << 3);
    X0c[(size_t)b * (NB_F0 * 16) + idx] =
        rne_bf16(X0g[(size_t)b * (NB_F0 * 16) + j * 16 + d]);
  }
}

// W f32 [128][39*Fi] -> Wf bf16 fragment-linear for 32x32x16 B-operand:
//   Wf[(((j*4 + t)*KC16 + c)*64 + lane)*8 + i]
//     = W[h = t*32 + (lane&31)][j, k = c*16 + (lane>>5)*8 + i]   (0 if k>=Fi)
__global__ void prep_w_kernel(const float* __restrict__ Wsrc,
                              unsigned short* __restrict__ Wdst,
                              int Fi, int kshift, int total) {
  int idx = blockIdx.x * 256 + threadIdx.x;
  if (idx >= total) return;
  const int i    = idx & 7;
  const int lane = (idx >> 3) & 63;
  const int c    = (idx >> 9) & ((1 << kshift) - 1);
  const int jt   = idx >> (9 + kshift);
  const int t    = jt & 3;
  const int j    = jt >> 2;
  const int h = t * 32 + (lane & 31);
  const int k = c * 16 + ((lane >> 5) << 3) + i;
  unsigned short v = 0;
  if (k < Fi) v = rne_bf16(Wsrc[(size_t)h * (NB_F0 * Fi) + j * Fi + k]);
  Wdst[idx] = v;
}

template <int FI_PAD, bool STORE_XN>
__global__ __launch_bounds__(256, 2) void cin_layer(
    const unsigned short* __restrict__ Wf,   // fragment-linear W (see prep)
    const unsigned short* __restrict__ XiT,  // [B][16][FI_PAD] bf16
    const unsigned short* __restrict__ X0c,  // [B][39][16] bf16, d-permuted
    const float* __restrict__ bias,          // [128]
    unsigned short* __restrict__ XnT,        // [B][16][128] bf16 (or unused)
    float* __restrict__ outp)                // d_out + layer*128, stride 384
{
  constexpr int KPASS = FI_PAD / 64;   // 1 or 2 K-passes of 64
  constexpr int KC16  = FI_PAD / 16;   // 16-wide k-chunks total
  constexpr int S     = NB_F0 * KPASS;

  __shared__ __attribute__((aligned(16))) unsigned short Wlds[2][2048]; // 2x4KB
  __shared__ __attribute__((aligned(16))) unsigned short x0s[32 * NB_F0 * 16];

  const int tid  = threadIdx.x;
  const int lane = tid & 63;
  const int wv   = tid >> 6;
  const int L    = lane >> 5;       // k-half selector
  const int col  = lane & 31;       // A row m / B col
  const int ht   = blockIdx.x >> 7;            // 0..3 (32 h each)
  const int bblk = (blockIdx.x & 127) * 32;    // 32 b per block
  const int bwave = bblk + wv * 8;             // 8 b per wave

  // ---- W DMA: wave wv stages chunk wv (1 KB) of the 4 KB stage tile ----
  auto dma_stage = [&](int s, int buf) {
    const int pass = (KPASS == 2 && s >= NB_F0) ? 1 : 0;
    const int j = s - pass * NB_F0;
    const unsigned short* src =
        Wf + (((size_t)(j * 4 + ht) * KC16) + pass * 4 + wv) * 512 + lane * 8;
    dma16(src, &Wlds[buf][wv * 512]);   // lane i -> +i*16B: fragment order
  };

  // ---- stage x0 factors (bf16 d-permuted, flat coalesced copy) ----
  {
    const unsigned short* src = X0c + (size_t)bblk * (NB_F0 * 16);
    for (int c = tid; c < (32 * NB_F0 * 16) / 8; c += 256)
      *(s16x8*)&x0s[c * 8] = *(const s16x8*)&src[c * 8];
  }
  dma_stage(0, 0);

  // ---- Xi A-fragments: chain P covers b' = 2P + (col>>4); resident regs ----
  s16x8 af[4][4];
  auto load_af = [&](int pass) {
#pragma unroll
    for (int P = 0; P < 4; ++P) {
      const unsigned short* base = XiT +
          ((size_t)(bwave + 2 * P + (col >> 4)) * 16 + (col & 15)) * FI_PAD +
          pass * 64 + L * 8;
#pragma unroll
      for (int c = 0; c < 4; ++c) af[P][c] = *(const s16x8*)(base + c * 16);
    }
  };
  load_af(0);

  f32x16 Xacc[4], kZero;
#pragma unroll
  for (int r = 0; r < 16; ++r) kZero[r] = 0.f;
#pragma unroll
  for (int P = 0; P < 4; ++P) Xacc[P] = kZero;

  const int x0base = (wv * 8) * (NB_F0 * 16) + L * 8;

  for (int s = 0; s < S; ++s) {
    __syncthreads();                    // publishes Wlds[s&1]; x0s on s==0
    if (s + 1 < S) dma_stage(s + 1, (s + 1) & 1);
    if (KPASS == 2 && s == NB_F0) load_af(1);   // af K-window switch

    const int j = (KPASS == 2 && s >= NB_F0) ? s - NB_F0 : s;
    const unsigned short* wb = &Wlds[s & 1][lane * 8];
    const s16x8 w0 = *(const s16x8*)(wb);
    const s16x8 w1 = *(const s16x8*)(wb + 512);
    const s16x8 w2 = *(const s16x8*)(wb + 1024);
    const s16x8 w3 = *(const s16x8*)(wb + 1536);

#pragma unroll
    for (int P = 0; P < 4; ++P) {
      f32x16 y;
      y = __builtin_amdgcn_mfma_f32_32x32x16_bf16(af[P][0], w0, kZero, 0, 0, 0);
      y = __builtin_amdgcn_mfma_f32_32x32x16_bf16(af[P][1], w1, y, 0, 0, 0);
      y = __builtin_amdgcn_mfma_f32_32x32x16_bf16(af[P][2], w2, y, 0, 0, 0);
      y = __builtin_amdgcn_mfma_f32_32x32x16_bf16(af[P][3], w3, y, 0, 0, 0);

      // x0 scale: regs 0-7 <- b'=2P (this lane's L 8-run), 8-15 <- b'=2P+1.
      // Unpack packed bf16 dwords to f32 pairs; elementwise_fma -> v_pk_fma_f32.
      const uint4 xu0 = *(const uint4*)
          &x0s[x0base + (2 * P + 0) * (NB_F0 * 16) + j * 16];
      const uint4 xu1 = *(const uint4*)
          &x0s[x0base + (2 * P + 1) * (NB_F0 * 16) + j * 16];
      const unsigned wd[8] = {xu0.x, xu0.y, xu0.z, xu0.w,
                              xu1.x, xu1.y, xu1.z, xu1.w};
      f32x16 xsc;
#pragma unroll
      for (int i = 0; i < 8; ++i) {
        xsc[2 * i]     = __uint_as_float(wd[i] << 16);
        xsc[2 * i + 1] = __uint_as_float(wd[i] & 0xffff0000u);
      }
      Xacc[P] = __builtin_elementwise_fma(xsc, y, Xacc[P]);
    }
  }

  // ---- epilogue ----
  const float bias_v = bias[ht * 32 + col];
#pragma unroll
  for (int P = 0; P < 4; ++P) {
#pragma unroll
    for (int bh = 0; bh < 2; ++bh) {
      const int b = bwave + 2 * P + bh;
      float v[8];
#pragma unroll
      for (int m = 0; m < 8; ++m) v[m] = Xacc[P][bh * 8 + m] + bias_v;
      if (STORE_XN) {
#pragma unroll
        for (int m = 0; m < 8; ++m) {
          const int d = (m & 3) + 8 * ((m >> 2) & 1) + 4 * L;
          XnT[((size_t)b * 16 + d) * NB_H + ht * 32 + col] = rne_bf16(v[m]);
        }
      }
      float tot = ((v[0] + v[1]) + (v[2] + v[3])) + ((v[4] + v[5]) + (v[6] + v[7]));
      tot += __shfl_xor(tot, 32);
      if (lane < 32) outp[(size_t)b * 384 + ht * 32 + lane] = tot;
    }
  }
}

extern "C" void kernel_launch(void* const* d_in, const int* in_sizes, int n_in,
                              void* d_out, int out_size, void* d_ws, size_t ws_size,
                              hipStream_t stream) {
  (void)in_sizes; (void)n_in; (void)out_size; (void)ws_size;
  const float* X0g = (const float*)d_in[0];
  const float* W0  = (const float*)d_in[1];
  const float* b0  = (const float*)d_in[2];
  const float* W1  = (const float*)d_in[3];
  const float* b1  = (const float*)d_in[4];
  const float* W2  = (const float*)d_in[5];
  const float* b2  = (const float*)d_in[6];
  float* out = (float*)d_out;

  char* p = (char*)d_ws;
  unsigned short* X0T = (unsigned short*)p; p += (size_t)NB_B * 16 * 64 * 2;
  unsigned short* X0c = (unsigned short*)p; p += (size_t)NB_B * NB_F0 * 16 * 2;
  unsigned short* X1T = (unsigned short*)p; p += (size_t)NB_B * 16 * 128 * 2;
  unsigned short* X2T = (unsigned short*)p; p += (size_t)NB_B * 16 * 128 * 2;
  unsigned short* Wf0 = (unsigned short*)p; p += (size_t)NB_F0 * 4 * 4 * 512 * 2;
  unsigned short* Wf1 = (unsigned short*)p; p += (size_t)NB_F0 * 4 * 8 * 512 * 2;
  unsigned short* Wf2 = (unsigned short*)p; p += (size_t)NB_F0 * 4 * 8 * 512 * 2;

  hipLaunchKernelGGL(prep_x0_kernel, dim3(NB_B), dim3(256), 0, stream,
                     X0g, X0T, X0c);
  const int tw0  = NB_F0 * 4 * 4 * 512;   // KC16=4
  const int tw12 = NB_F0 * 4 * 8 * 512;   // KC16=8
  hipLaunchKernelGGL(prep_w_kernel, dim3((tw0 + 255) / 256), dim3(256), 0, stream,
                     W0, Wf0, 39, 2, tw0);
  hipLaunchKernelGGL(prep_w_kernel, dim3((tw12 + 255) / 256), dim3(256), 0, stream,
                     W1, Wf1, 128, 3, tw12);
  hipLaunchKernelGGL(prep_w_kernel, dim3((tw12 + 255) / 256), dim3(256), 0, stream,
                     W2, Wf2, 128, 3, tw12);

  hipLaunchKernelGGL((cin_layer<64, true>),   dim3(512), dim3(256), 0, stream,
                     Wf0, X0T, X0c, b0, X1T, out + 0);
  hipLaunchKernelGGL((cin_layer<128, true>),  dim3(512), dim3(256), 0, stream,
                     Wf1, X1T, X0c, b1, X2T, out + 128);
  hipLaunchKernelGGL((cin_layer<128, false>), dim3(512), dim3(256), 0, stream,
                     Wf2, X2T, X0c, b2, (unsigned short*)nullptr, out + 256);
}